// Round 10
// baseline (255.605 us; speedup 1.0000x reference)
//
#include <hip/hip_runtime.h>
#include <math.h>

#define L 8
#define D 512
#define DD (D*D)
#define P 128
#define H 8
#define HD 64
#define B 2
#define NS 4
#define S 384
#define BS (B*S)                     // 768
#define XN (BS*D)                    // 393216
#define SS ((size_t)S*S)             // 147456
#define BHSS ((size_t)B*H*S*S)       // 2359296
#define NSLAB 32                     // part slabs (phaseA uses 0..16, final 0..32)

typedef short bf16x8 __attribute__((ext_vector_type(8)));
typedef float f32x4 __attribute__((ext_vector_type(4)));

__device__ __forceinline__ unsigned short f2b(float f) {
    unsigned u = __float_as_uint(f);
    unsigned r = (u + 0x7FFF + ((u >> 16) & 1)) >> 16;
    return (unsigned short)r;
}
__device__ __forceinline__ float b2f(unsigned short u) {
    return __uint_as_float(((unsigned)u) << 16);
}

// ---------------- init: x = msa[:,0] (f32 + bf16), part = 0, wpbT bf16 ----------------
__global__ __launch_bounds__(256) void k_init(const float* __restrict__ msa,
                                              float* __restrict__ x,
                                              unsigned short* __restrict__ xb,
                                              float* __restrict__ part,
                                              const float* __restrict__ Wpb,
                                              unsigned short* __restrict__ wpbT) {
    int idx = blockIdx.x * 256 + threadIdx.x;
    if (idx < XN) {
        int b = idx / (S * D);
        int rem = idx - b * (S * D);
        float v = msa[(size_t)b * NS * S * D + rem];
        x[idx] = v;
        xb[idx] = f2b(v);
    }
    if (idx < NSLAB * BS * 3) part[idx] = 0.f;
    if (idx < 64 * P) {               // Wpb [l][p][h] -> wpbT [l*8+h][p] bf16
        int l = idx >> 10, rem = idx & 1023;
        int p = rem >> 3, h = rem & 7;
        wpbT[(size_t)((l << 3) | h) * P + p] = f2b(Wpb[idx]);
    }
}

// ---------------- weight prep: transpose+convert to bf16 [N][K] ----------------
// z: 0-7 Wq[l], 8-15 Wk, 16-23 Wv, 24-31 Wo, 32 Wb1, 33 Wc1 (N=256)
__global__ __launch_bounds__(256) void k_prep(const float* __restrict__ Wq,
        const float* __restrict__ Wk, const float* __restrict__ Wv,
        const float* __restrict__ Wo, const float* __restrict__ Wb1,
        const float* __restrict__ Wc1, unsigned short* __restrict__ wt) {
    __shared__ float ts[64][65];
    const int z = blockIdx.z;
    const float* src; int N = 512;
    if (z < 8)       src = Wq + (size_t)z * DD;
    else if (z < 16) src = Wk + (size_t)(z - 8) * DD;
    else if (z < 24) src = Wv + (size_t)(z - 16) * DD;
    else if (z < 32) src = Wo + (size_t)(z - 24) * DD;
    else if (z == 32) src = Wb1;
    else { src = Wc1; N = 256; }
    unsigned short* dst = wt + (size_t)z * DD;

    const int n0 = blockIdx.x * 64, k0 = blockIdx.y * 64;
    if (n0 >= N) return;
    const int t = threadIdx.x;
    #pragma unroll
    for (int m = 0; m < 16; m++) {
        int f = t + m * 256;
        int r = f >> 6, c = f & 63;
        ts[r][c] = src[(size_t)(k0 + r) * N + n0 + c];
    }
    __syncthreads();
    #pragma unroll
    for (int m = 0; m < 4; m++) {
        int o4 = t + m * 256;
        int nr = o4 >> 4, k4 = o4 & 15;
        ushort4 pk;
        pk.x = f2b(ts[k4 * 4 + 0][nr]);
        pk.y = f2b(ts[k4 * 4 + 1][nr]);
        pk.z = f2b(ts[k4 * 4 + 2][nr]);
        pk.w = f2b(ts[k4 * 4 + 3][nr]);
        *(ushort4*)&dst[(size_t)(n0 + nr) * 512 + k0 + k4 * 4] = pk;
    }
}

// ---------------- pair bias via MFMA: bias[l,b,h,i,j] (bf16 out) ----------------
__global__ __launch_bounds__(256) void k_biasm(const float* __restrict__ pair,
        const unsigned short* __restrict__ wpbT, const float* __restrict__ bpb,
        unsigned short* __restrict__ bias) {
    __shared__ unsigned short Ws[64][136];
    __shared__ unsigned short Ps[64][136];
    const int t = threadIdx.x;
    const int lane = t & 63, w = t >> 6;
    const int jt = blockIdx.x, i = blockIdx.y, b = blockIdx.z;

    #pragma unroll
    for (int m = 0; m < 4; m++) {
        int f = t + m * 256;              // 1024 int4 = 64 rows x 128 ushorts
        int r = f >> 4, c8 = f & 15;
        *(int4*)&Ws[r][c8 * 8] = *(const int4*)&wpbT[(size_t)r * P + c8 * 8];
    }
    const float* prow = pair + (((size_t)b * S + i) * S + jt * 64) * P;
    #pragma unroll
    for (int m = 0; m < 8; m++) {
        int f = (t + m * 256) * 4;
        int r = f >> 7, c = f & 127;
        float4 pv = *(const float4*)&prow[f];
        ushort4 u;
        u.x = f2b(pv.x); u.y = f2b(pv.y); u.z = f2b(pv.z); u.w = f2b(pv.w);
        *(ushort4*)&Ps[r][c] = u;
    }
    __syncthreads();

    f32x4 acc[4];
    #pragma unroll
    for (int mi = 0; mi < 4; mi++) { acc[mi][0] = 0.f; acc[mi][1] = 0.f; acc[mi][2] = 0.f; acc[mi][3] = 0.f; }
    #pragma unroll
    for (int ks = 0; ks < 4; ks++) {
        bf16x8 bv = *(const bf16x8*)&Ps[w * 16 + (lane & 15)][ks * 32 + (lane >> 4) * 8];
        #pragma unroll
        for (int mi = 0; mi < 4; mi++) {
            bf16x8 av = *(const bf16x8*)&Ws[mi * 16 + (lane & 15)][ks * 32 + (lane >> 4) * 8];
            acc[mi] = __builtin_amdgcn_mfma_f32_16x16x32_bf16(av, bv, acc[mi], 0, 0, 0);
        }
    }
    const int j = jt * 64 + w * 16 + (lane & 15);
    #pragma unroll
    for (int mi = 0; mi < 4; mi++)
        #pragma unroll
        for (int reg = 0; reg < 4; reg++) {
            int lh = mi * 16 + (lane >> 4) * 4 + reg;
            float v = acc[mi][reg] + bpb[lh];
            size_t plane = ((size_t)(lh >> 3) * B + b) * H + (lh & 7);
            bias[plane * SS + (size_t)i * S + j] = f2b(v);
        }
}

// ================= 64x64-tile GEMM core, 4 waves x 32x32/wave, dbuf =================
// requires: srow = t>>3, sc0 = (t&7)*8, wr = (t>>6)>>1, wc = (t>>6)&1, lane
#define GEMM64_CORE(Abase, Wbase)                                              \
    f32x4 acc[2][2];                                                           \
    _Pragma("unroll")                                                          \
    for (int qz = 0; qz < 2; qz++)                                             \
        _Pragma("unroll")                                                      \
        for (int rz = 0; rz < 2; rz++) {                                       \
            acc[qz][rz][0] = 0.f; acc[qz][rz][1] = 0.f;                        \
            acc[qz][rz][2] = 0.f; acc[qz][rz][3] = 0.f;                        \
        }                                                                      \
    {                                                                          \
        const unsigned short* pa0 = &(Abase)[(size_t)(m0 + srow) * 512 + sc0]; \
        const unsigned short* pa1 = pa0 + 32 * 512;                            \
        const unsigned short* pb0 = &(Wbase)[(size_t)(n0 + srow) * 512 + sc0]; \
        const unsigned short* pb1 = pb0 + 32 * 512;                            \
        int4 ra0 = *(const int4*)pa0, ra1 = *(const int4*)pa1;                 \
        int4 rb0 = *(const int4*)pb0, rb1 = *(const int4*)pb1;                 \
        *(int4*)&As[0][srow][sc0] = ra0;  *(int4*)&As[0][srow + 32][sc0] = ra1;\
        *(int4*)&Bs[0][srow][sc0] = rb0;  *(int4*)&Bs[0][srow + 32][sc0] = rb1;\
        __syncthreads();                                                       \
        int cur = 0;                                                           \
        for (int kt = 0; kt < 512; kt += 64) {                                 \
            if (kt + 64 < 512) {                                               \
                ra0 = *(const int4*)(pa0 + kt + 64);                           \
                ra1 = *(const int4*)(pa1 + kt + 64);                           \
                rb0 = *(const int4*)(pb0 + kt + 64);                           \
                rb1 = *(const int4*)(pb1 + kt + 64);                           \
            }                                                                  \
            _Pragma("unroll")                                                  \
            for (int kk = 0; kk < 2; kk++) {                                   \
                bf16x8 a0 = *(const bf16x8*)&As[cur][wr * 32 + (lane & 15)][kk * 32 + (lane >> 4) * 8];      \
                bf16x8 a1 = *(const bf16x8*)&As[cur][wr * 32 + 16 + (lane & 15)][kk * 32 + (lane >> 4) * 8]; \
                bf16x8 b0 = *(const bf16x8*)&Bs[cur][wc * 32 + (lane & 15)][kk * 32 + (lane >> 4) * 8];      \
                bf16x8 b1 = *(const bf16x8*)&Bs[cur][wc * 32 + 16 + (lane & 15)][kk * 32 + (lane >> 4) * 8]; \
                acc[0][0] = __builtin_amdgcn_mfma_f32_16x16x32_bf16(a0, b0, acc[0][0], 0, 0, 0); \
                acc[0][1] = __builtin_amdgcn_mfma_f32_16x16x32_bf16(a0, b1, acc[0][1], 0, 0, 0); \
                acc[1][0] = __builtin_amdgcn_mfma_f32_16x16x32_bf16(a1, b0, acc[1][0], 0, 0, 0); \
                acc[1][1] = __builtin_amdgcn_mfma_f32_16x16x32_bf16(a1, b1, acc[1][1], 0, 0, 0); \
            }                                                                  \
            if (kt + 64 < 512) {                                               \
                *(int4*)&As[cur ^ 1][srow][sc0] = ra0;                         \
                *(int4*)&As[cur ^ 1][srow + 32][sc0] = ra1;                    \
                *(int4*)&Bs[cur ^ 1][srow][sc0] = rb0;                         \
                *(int4*)&Bs[cur ^ 1][srow + 32][sc0] = rb1;                    \
            }                                                                  \
            __syncthreads();                                                   \
            cur ^= 1;                                                          \
        }                                                                      \
    }

// ================= 32x32-tile GEMM core (k_wo / k_final), dbuf =================
#define GEMM32_CORE(Abase, Wbase)                                              \
    f32x4 acc; acc[0] = 0.f; acc[1] = 0.f; acc[2] = 0.f; acc[3] = 0.f;         \
    {                                                                          \
        const unsigned short* pa = &(Abase)[(size_t)(m0 + sr) * 512 + scc];    \
        const unsigned short* pb = &(Wbase)[(size_t)(n0 + sr) * 512 + scc];    \
        int4 ra = *(const int4*)pa;                                            \
        int4 rb = *(const int4*)pb;                                            \
        *(int4*)&As[0][sr][scc] = ra;                                          \
        *(int4*)&Bs[0][sr][scc] = rb;                                          \
        __syncthreads();                                                       \
        int cur = 0;                                                           \
        for (int kt = 0; kt < 512; kt += 64) {                                 \
            if (kt + 64 < 512) {                                               \
                ra = *(const int4*)(pa + kt + 64);                             \
                rb = *(const int4*)(pb + kt + 64);                             \
            }                                                                  \
            _Pragma("unroll")                                                  \
            for (int kk = 0; kk < 2; kk++) {                                   \
                bf16x8 a = *(const bf16x8*)&As[cur][wr * 16 + (lane & 15)][kk * 32 + (lane >> 4) * 8]; \
                bf16x8 bb = *(const bf16x8*)&Bs[cur][wc * 16 + (lane & 15)][kk * 32 + (lane >> 4) * 8]; \
                acc = __builtin_amdgcn_mfma_f32_16x16x32_bf16(a, bb, acc, 0, 0, 0); \
            }                                                                  \
            if (kt + 64 < 512) {                                               \
                *(int4*)&As[cur ^ 1][sr][scc] = ra;                            \
                *(int4*)&Bs[cur ^ 1][sr][scc] = rb;                            \
            }                                                                  \
            __syncthreads();                                                   \
            cur ^= 1;                                                          \
        }                                                                      \
    }

// ---------------- phase A: z=0,1,2 -> Q,K,V projections; z=3 -> Wb1(prev layer) ----------------
// 64x64 tiles: grid (8, 12, z)
__global__ __launch_bounds__(256) void k_phaseA(const unsigned short* __restrict__ xb,
        const unsigned short* __restrict__ wt,
        const float* __restrict__ bq, const float* __restrict__ bk, const float* __restrict__ bv,
        unsigned short* __restrict__ qbb, unsigned short* __restrict__ kbb,
        unsigned short* __restrict__ vtb,
        const float* __restrict__ bb1, const float* __restrict__ Wb2g,
        float* __restrict__ part, int l) {
    __shared__ unsigned short As[2][64][72];
    __shared__ unsigned short Bs[2][64][72];
    const int t = threadIdx.x, lane = t & 63;
    const int w = t >> 6, wr = w >> 1, wc = w & 1;
    const int z = blockIdx.z;
    const int m0 = blockIdx.y * 64, n0 = blockIdx.x * 64;
    const int srow = t >> 3, sc0 = (t & 7) * 8;

    const unsigned short* Wt;
    const float* bias;
    if (z == 0)      { Wt = wt + (size_t)l * DD;        bias = bq + l * D; }
    else if (z == 1) { Wt = wt + (size_t)(8 + l) * DD;  bias = bk + l * D; }
    else if (z == 2) { Wt = wt + (size_t)(16 + l) * DD; bias = bv + l * D; }
    else             { Wt = wt + (size_t)32 * DD;       bias = bb1; }

    GEMM64_CORE(xb, Wt)

    if (z < 3) {
        unsigned short* out = (z == 0) ? qbb : (z == 1) ? kbb : vtb;
        #pragma unroll
        for (int ac = 0; ac < 2; ac++) {
            int col = n0 + wc * 32 + ac * 16 + (lane & 15);
            float bcol = bias[col];
            int h = col >> 6, d = col & 63;
            #pragma unroll
            for (int ar = 0; ar < 2; ar++)
                #pragma unroll
                for (int reg = 0; reg < 4; reg++) {
                    int row = m0 + wr * 32 + ar * 16 + (lane >> 4) * 4 + reg;
                    int b = row / S, i = row - b * S;
                    float v = acc[ar][ac][reg] + bcol;
                    if (z < 2) out[(((size_t)b * H + h) * S + i) * HD + d] = f2b(v);
                    else       out[(((size_t)b * H + h) * HD + d) * S + i] = f2b(v);
                }
        }
    } else {
        float bc[2], w20[2], w21[2], w22[2];
        #pragma unroll
        for (int ac = 0; ac < 2; ac++) {
            int col = n0 + wc * 32 + ac * 16 + (lane & 15);
            bc[ac] = bias[col];
            w20[ac] = Wb2g[col * 6 + 0];
            w21[ac] = Wb2g[col * 6 + 1];
            w22[ac] = Wb2g[col * 6 + 2];
        }
        #pragma unroll
        for (int ar = 0; ar < 2; ar++)
            #pragma unroll
            for (int reg = 0; reg < 4; reg++) {
                float p0 = 0.f, p1 = 0.f, p2 = 0.f;
                #pragma unroll
                for (int ac = 0; ac < 2; ac++) {
                    float v = fmaxf(acc[ar][ac][reg] + bc[ac], 0.f);
                    p0 += v * w20[ac]; p1 += v * w21[ac]; p2 += v * w22[ac];
                }
                #pragma unroll
                for (int m = 1; m < 16; m <<= 1) {
                    p0 += __shfl_xor(p0, m);
                    p1 += __shfl_xor(p1, m);
                    p2 += __shfl_xor(p2, m);
                }
                if ((lane & 15) == 0) {
                    int row = m0 + wr * 32 + ar * 16 + (lane >> 4) * 4 + reg;
                    float* pp = &part[((size_t)(blockIdx.x * 2 + wc) * BS + row) * 3];
                    pp[0] += p0; pp[1] += p1; pp[2] += p2;
                }
            }
    }
}

// ---------------- Wo GEMM + residual -> x (f32) and xb (bf16) ----------------
__global__ __launch_bounds__(256) void k_wo(const unsigned short* __restrict__ aob,
        const unsigned short* __restrict__ wt, const float* __restrict__ bo,
        float* __restrict__ x, unsigned short* __restrict__ xb, int l) {
    __shared__ unsigned short As[2][32][72];
    __shared__ unsigned short Bs[2][32][72];
    const int t = threadIdx.x, lane = t & 63;
    const int w = t >> 6, wr = w >> 1, wc = w & 1;
    const int m0 = blockIdx.y * 32, n0 = blockIdx.x * 32;
    const int sr = t >> 3, scc = (t & 7) * 8;
    const unsigned short* Wt = wt + (size_t)(24 + l) * DD;

    GEMM32_CORE(aob, Wt)

    const int col = n0 + wc * 16 + (lane & 15);
    const float bcol = bo[l * D + col];
    #pragma unroll
    for (int reg = 0; reg < 4; reg++) {
        int row = m0 + wr * 16 + (lane >> 4) * 4 + reg;
        float v = acc[reg] + bcol + x[(size_t)row * D + col];
        x[(size_t)row * D + col] = v;
        xb[(size_t)row * D + col] = f2b(v);
    }
}

// ---------------- final: z=0 -> Wb1(L-1) coords partial; z=1 -> Wc1 relu -> hc ----------------
__global__ __launch_bounds__(256) void k_final(const unsigned short* __restrict__ xb,
        const unsigned short* __restrict__ wt,
        const float* __restrict__ bb1, const float* __restrict__ Wb2g, float* __restrict__ part,
        const float* __restrict__ bc1, float* __restrict__ hc) {
    __shared__ unsigned short As[2][32][72];
    __shared__ unsigned short Bs[2][32][72];
    const int t = threadIdx.x, lane = t & 63;
    const int w = t >> 6, wr = w >> 1, wc = w & 1;
    const int z = blockIdx.z;
    if (z == 1 && blockIdx.x >= 8) return;
    const int m0 = blockIdx.y * 32, n0 = blockIdx.x * 32;
    const int sr = t >> 3, scc = (t & 7) * 8;
    const unsigned short* Wt = (z == 0) ? wt + (size_t)32 * DD : wt + (size_t)33 * DD;

    GEMM32_CORE(xb, Wt)

    const int col = n0 + wc * 16 + (lane & 15);
    if (z == 0) {
        const float bcol = bb1[col];
        const float w20 = Wb2g[col * 6 + 0];
        const float w21 = Wb2g[col * 6 + 1];
        const float w22 = Wb2g[col * 6 + 2];
        #pragma unroll
        for (int reg = 0; reg < 4; reg++) {
            float v = fmaxf(acc[reg] + bcol, 0.f);
            float p0 = v * w20, p1 = v * w21, p2 = v * w22;
            #pragma unroll
            for (int m = 1; m < 16; m <<= 1) {
                p0 += __shfl_xor(p0, m);
                p1 += __shfl_xor(p1, m);
                p2 += __shfl_xor(p2, m);
            }
            if ((lane & 15) == 0) {
                int row = m0 + wr * 16 + (lane >> 4) * 4 + reg;
                float* pp = &part[((size_t)(blockIdx.x * 2 + wc) * BS + row) * 3];
                pp[0] += p0; pp[1] += p1; pp[2] += p2;
            }
        }
    } else {
        const float bcol = bc1[col];
        #pragma unroll
        for (int reg = 0; reg < 4; reg++) {
            int row = m0 + wr * 16 + (lane >> 4) * 4 + reg;
            hc[(size_t)row * 256 + col] = fmaxf(acc[reg] + bcol, 0.f);
        }
    }
}

// ---------------- MFMA flash attention, double-buffered K/V staging ----------------
__global__ __launch_bounds__(256) void k_attnm(const unsigned short* __restrict__ qb,
        const unsigned short* __restrict__ kb, const unsigned short* __restrict__ vt,
        const unsigned short* __restrict__ biasL, unsigned short* __restrict__ aob) {
    __shared__ unsigned short qs[16][72];
    __shared__ unsigned short kv[2][64][72];
    __shared__ float scs[16][392];
    __shared__ unsigned short pbs[16][392];
    __shared__ float invs[16];

    const int t = threadIdx.x, lane = t & 63, w = t >> 6;
    const int i0 = blockIdx.x * 16;
    const int h = blockIdx.y, b = blockIdx.z;
    const size_t bh = (size_t)b * H + h;
    const unsigned short* qp = qb + (bh * S + i0) * HD;
    const unsigned short* kp = kb + bh * S * HD;
    const unsigned short* vp = vt + bh * HD * S;
    const unsigned short* bp = biasL + bh * SS + (size_t)i0 * S;

    const int str = t >> 3, stc = (t & 7) * 8;   // 64x64 staging: rows str/str+32

    // prologue: stage Q (16x64), bias (16x384), K tile 0
    if (t < 128) {
        int r = t >> 3, c = (t & 7) * 8;
        *(int4*)&qs[r][c] = *(const int4*)&qp[r * HD + c];
    }
    #pragma unroll
    for (int m = 0; m < 3; m++) {
        int f = t + m * 256;
        int r = f / 48, c = (f % 48) * 8;
        *(int4*)&pbs[r][c] = *(const int4*)&bp[(size_t)r * S + c];
    }
    *(int4*)&kv[0][str][stc]      = *(const int4*)&kp[(size_t)str * HD + stc];
    *(int4*)&kv[0][32 + str][stc] = *(const int4*)&kp[(size_t)(32 + str) * HD + stc];
    __syncthreads();

    bf16x8 qa0 = *(const bf16x8*)&qs[lane & 15][(lane >> 4) * 8];
    bf16x8 qa1 = *(const bf16x8*)&qs[lane & 15][32 + (lane >> 4) * 8];

    // ---- QK^T * scale + bias -> scs (dbuf: 1 barrier/tile) ----
    int cur = 0;
    for (int jt = 0; jt < 6; jt++) {
        int4 r0, r1;
        if (jt < 5) {
            r0 = *(const int4*)&kp[(size_t)((jt + 1) * 64 + str) * HD + stc];
            r1 = *(const int4*)&kp[(size_t)((jt + 1) * 64 + 32 + str) * HD + stc];
        }
        f32x4 acc; acc[0] = 0.f; acc[1] = 0.f; acc[2] = 0.f; acc[3] = 0.f;
        bf16x8 kb0 = *(const bf16x8*)&kv[cur][w * 16 + (lane & 15)][(lane >> 4) * 8];
        bf16x8 kb1 = *(const bf16x8*)&kv[cur][w * 16 + (lane & 15)][32 + (lane >> 4) * 8];
        acc = __builtin_amdgcn_mfma_f32_16x16x32_bf16(qa0, kb0, acc, 0, 0, 0);
        acc = __builtin_amdgcn_mfma_f32_16x16x32_bf16(qa1, kb1, acc, 0, 0, 0);
        const int col = jt * 64 + w * 16 + (lane & 15);
        #pragma unroll
        for (int reg = 0; reg < 4; reg++) {
            int row = (lane >> 4) * 4 + reg;
            scs[row][col] = acc[reg] * 0.125f + b2f(pbs[row][col]);
        }
        if (jt < 5) {
            *(int4*)&kv[cur ^ 1][str][stc]      = r0;
            *(int4*)&kv[cur ^ 1][32 + str][stc] = r1;
        }
        __syncthreads();
        cur ^= 1;
    }

    // ---- softmax (V tile 0 prefetch overlapped) ----
    int4 v0 = *(const int4*)&vp[(size_t)str * S + stc];
    int4 v1 = *(const int4*)&vp[(size_t)(32 + str) * S + stc];
    const int i = t >> 4, sub = t & 15;
    float mx = -1e30f;
    #pragma unroll
    for (int m = 0; m < 24; m++) mx = fmaxf(mx, scs[i][sub + m * 16]);
    #pragma unroll
    for (int m = 1; m < 16; m <<= 1) mx = fmaxf(mx, __shfl_xor(mx, m));
    float pv_[24];
    float sum = 0.f;
    #pragma unroll
    for (int m = 0; m < 24; m++) {
        float p = __expf(scs[i][sub + m * 16] - mx);
        pv_[m] = p;
        sum += p;
    }
    #pragma unroll
    for (int m = 1; m < 16; m <<= 1) sum += __shfl_xor(sum, m);
    if (sub == 0) invs[i] = 1.f / sum;
    #pragma unroll
    for (int m = 0; m < 24; m++) pbs[i][sub + m * 16] = f2b(pv_[m]);
    *(int4*)&kv[0][str][stc]      = v0;
    *(int4*)&kv[0][32 + str][stc] = v1;
    __syncthreads();

    // ---- PV (dbuf) ----
    f32x4 oacc; oacc[0] = 0.f; oacc[1] = 0.f; oacc[2] = 0.f; oacc[3] = 0.f;
    int vc = 0;
    for (int jt = 0; jt < 6; jt++) {
        int4 w0, w1;
        if (jt < 5) {
            w0 = *(const int4*)&vp[(size_t)str * S + (jt + 1) * 64 + stc];
            w1 = *(const int4*)&vp[(size_t)(32 + str) * S + (jt + 1) * 64 + stc];
        }
        #pragma unroll
        for (int kk = 0; kk < 2; kk++) {
            bf16x8 pa = *(const bf16x8*)&pbs[lane & 15][jt * 64 + kk * 32 + (lane >> 4) * 8];
            bf16x8 bb = *(const bf16x8*)&kv[vc][w * 16 + (lane & 15)][kk * 32 + (lane >> 4) * 8];
            oacc = __builtin_amdgcn_mfma_f32_16x16x32_bf16(pa, bb, oacc, 0, 0, 0);
        }
        if (jt < 5) {
            *(int4*)&kv[vc ^ 1][str][stc]      = w0;
            *(int4*)&kv[vc ^ 1][32 + str][stc] = w1;
        }
        __syncthreads();
        vc ^= 1;
    }
    #pragma unroll
    for (int reg = 0; reg < 4; reg++) {
        int row = (lane >> 4) * 4 + reg;
        int d = w * 16 + (lane & 15);
        float v = oacc[reg] * invs[row];
        aob[((size_t)(b * S + i0 + row)) * D + h * HD + d] = f2b(v);
    }
}

// ---------------- confidence + coords assembly ----------------
__global__ __launch_bounds__(256) void k_conf(const float* __restrict__ hc,
        const float* __restrict__ Wc2, const float* __restrict__ bc2,
        const float* __restrict__ part, const float* __restrict__ bb2,
        float* __restrict__ out) {
    const int wv = threadIdx.x >> 6, lane = threadIdx.x & 63;
    const int row = blockIdx.x * 4 + wv;
    const float* hr = hc + (size_t)row * 256;
    float p = 0.f;
    #pragma unroll
    for (int m = 0; m < 4; m++) p += hr[m * 64 + lane] * Wc2[m * 64 + lane];
    #pragma unroll
    for (int m = 32; m; m >>= 1) p += __shfl_xor(p, m);
    if (lane == 0) out[B * S * 3 + row] = 1.f / (1.f + __expf(-(p + bc2[0])));
    int ci = blockIdx.x * 12 + threadIdx.x;
    if (threadIdx.x < 12) {
        int r = ci / 3, c = ci - r * 3;
        float s = 8.f * bb2[c];
        #pragma unroll
        for (int nb = 0; nb < NSLAB; nb++) s += part[((size_t)nb * BS + r) * 3 + c];
        out[ci] = s;
    }
}

extern "C" void kernel_launch(void* const* d_in, const int* in_sizes, int n_in,
                              void* d_out, int out_size, void* d_ws, size_t ws_size,
                              hipStream_t stream) {
    const float* msa = (const float*)d_in[0];
    const float* pair = (const float*)d_in[1];
    const float* Wq = (const float*)d_in[2];
    const float* bq = (const float*)d_in[3];
    const float* Wk = (const float*)d_in[4];
    const float* bk = (const float*)d_in[5];
    const float* Wv = (const float*)d_in[6];
    const float* bv = (const float*)d_in[7];
    const float* Wpb = (const float*)d_in[8];
    const float* bpb = (const float*)d_in[9];
    const float* Wo = (const float*)d_in[10];
    const float* bo = (const float*)d_in[11];
    const float* Wb1 = (const float*)d_in[12];
    const float* bb1 = (const float*)d_in[13];
    const float* Wb2 = (const float*)d_in[14];
    const float* bb2 = (const float*)d_in[15];
    const float* Wc1 = (const float*)d_in[16];
    const float* bc1 = (const float*)d_in[17];
    const float* Wc2 = (const float*)d_in[18];
    const float* bc2 = (const float*)d_in[19];

    char* base = (char*)d_ws;
    float* x    = (float*)base;            base += (size_t)XN * 4;
    float* hc   = (float*)base;            base += (size_t)BS * 256 * 4;
    float* part = (float*)base;            base += (size_t)NSLAB * BS * 3 * 4;
    unsigned short* xb  = (unsigned short*)base;  base += (size_t)XN * 2;
    unsigned short* aob = (unsigned short*)base;  base += (size_t)XN * 2;
    unsigned short* qbb = (unsigned short*)base;  base += (size_t)XN * 2;
    unsigned short* kbb = (unsigned short*)base;  base += (size_t)XN * 2;
    unsigned short* vtb = (unsigned short*)base;  base += (size_t)XN * 2;
    unsigned short* wt  = (unsigned short*)base;  base += (size_t)34 * DD * 2;
    unsigned short* wpbT = (unsigned short*)base; base += (size_t)64 * P * 2;
    unsigned short* biasb = (unsigned short*)base;

    k_prep<<<dim3(8, 8, 34), 256, 0, stream>>>(Wq, Wk, Wv, Wo, Wb1, Wc1, wt);
    k_init<<<dim3(1536), 256, 0, stream>>>(msa, x, xb, part, Wpb, wpbT);
    k_biasm<<<dim3(6, S, B), 256, 0, stream>>>(pair, wpbT, bpb, biasb);

    for (int l = 0; l < L; ++l) {
        k_phaseA<<<dim3(8, 12, l == 0 ? 3 : 4), 256, 0, stream>>>(xb, wt,
            bq, bk, bv, qbb, kbb, vtb, bb1, Wb2, part, l);
        k_attnm<<<dim3(S / 16, H, B), 256, 0, stream>>>(qbb, kbb, vtb,
            biasb + (size_t)l * BHSS, aob);
        k_wo<<<dim3(16, 24), 256, 0, stream>>>(aob, wt, bo, x, xb, l);
    }

    k_final<<<dim3(16, 24, 2), 256, 0, stream>>>(xb, wt, bb1, Wb2, part, bc1, hc);
    k_conf<<<dim3(BS / 4), 256, 0, stream>>>(hc, Wc2, bc2, part, bb2, (float*)d_out);
}